// Round 3
// baseline (71.362 us; speedup 1.0000x reference)
//
#include <hip/hip_runtime.h>
#include <hip/hip_cooperative_groups.h>
#include <math.h>

namespace cg = cooperative_groups;

#define NF 64        // IN_FEATS
#define NBLOCKS 1024 // 4 blocks/CU on 256 CUs — safely co-resident (4 waves/block)
#define NTHREADS 256

// ---------------------------------------------------------------------------
// Single cooperative kernel.
// Phase 1 (grid-stride): S[n] = (h[n]·W_u, h[n]·W_v). 4 nodes/wave, float4
//   loads (1 KB contiguous per wave iteration), 16-lane segmented butterfly.
// grid.sync()
// Phase 2 (grid-stride): out[e] = sigmoid(S[src[e]].x + S[dst[e]].y + b),
//   4 edges/thread, int4 index loads, float4 stores. S (400 KB) is L2-hot.
// Index dtype (int64 vs int32) detected per-wave from the first 512 B of
// src: int64 node ids < 2^31 have every odd dword == 0.
// ---------------------------------------------------------------------------
__global__ void fused_kernel(const float4* __restrict__ h4,
                             const float4* __restrict__ W4,
                             float2* __restrict__ S, int nNodes,
                             const void* __restrict__ srcv,
                             const void* __restrict__ dstv,
                             const float* __restrict__ b,
                             float4* __restrict__ out4, int nE4) {
    cg::grid_group grid = cg::this_grid();

    int lane = threadIdx.x & 63;

    // Per-wave index-dtype detection (same 512 B for every wave — L2 broadcast).
    int odd = ((const int*)srcv)[2 * lane + 1];
    unsigned long long bal = __ballot(odd == 0);
    bool is64 = (bal == ~0ull);  // wave-uniform

    int gtid     = blockIdx.x * blockDim.x + threadIdx.x;
    int nThreads = gridDim.x * blockDim.x;

    // -------- Phase 1: node scores --------
    int group = lane >> 4;   // which of the wave's 4 nodes
    int fl    = lane & 15;   // feature block (4 floats)
    float4 wu = W4[fl];
    float4 wv = W4[16 + fl];
    int waveId = gtid >> 6;
    int nWaves = nThreads >> 6;
    for (int node = waveId * 4 + group; node < nNodes; node += nWaves * 4) {
        float4 x = h4[node * 16 + fl];
        float su = x.x * wu.x + x.y * wu.y + x.z * wu.z + x.w * wu.w;
        float sv = x.x * wv.x + x.y * wv.y + x.z * wv.z + x.w * wv.w;
        #pragma unroll
        for (int off = 1; off < 16; off <<= 1) {  // stays in 16-lane segment
            su += __shfl_xor(su, off, 64);
            sv += __shfl_xor(sv, off, 64);
        }
        if (fl == 0) S[node] = make_float2(su, sv);
    }

    grid.sync();  // S visible device-wide

    // -------- Phase 2: edges --------
    float bias = b[0];
    for (int t = gtid; t < nE4; t += nThreads) {
        int s0, s1, s2, s3, d0, d1, d2, d3;
        if (is64) {
            const int4* sp = (const int4*)srcv;
            const int4* dp = (const int4*)dstv;
            int4 a = sp[2 * t], c = sp[2 * t + 1];
            int4 e = dp[2 * t], f = dp[2 * t + 1];
            s0 = a.x; s1 = a.z; s2 = c.x; s3 = c.z;
            d0 = e.x; d1 = e.z; d2 = f.x; d3 = f.z;
        } else {
            int4 a = ((const int4*)srcv)[t];
            int4 e = ((const int4*)dstv)[t];
            s0 = a.x; s1 = a.y; s2 = a.z; s3 = a.w;
            d0 = e.x; d1 = e.y; d2 = e.z; d3 = e.w;
        }
        float2 A = S[s0], B = S[s1], C = S[s2], D = S[s3];
        float2 E = S[d0], F = S[d1], G = S[d2], H = S[d3];
        float l0 = A.x + E.y + bias;
        float l1 = B.x + F.y + bias;
        float l2 = C.x + G.y + bias;
        float l3 = D.x + H.y + bias;
        out4[t] = make_float4(1.0f / (1.0f + __expf(-l0)),
                              1.0f / (1.0f + __expf(-l1)),
                              1.0f / (1.0f + __expf(-l2)),
                              1.0f / (1.0f + __expf(-l3)));
    }
}

extern "C" void kernel_launch(void* const* d_in, const int* in_sizes, int n_in,
                              void* d_out, int out_size, void* d_ws, size_t ws_size,
                              hipStream_t stream) {
    const float4* h4  = (const float4*)d_in[0];
    const void*   src = d_in[1];
    const void*   dst = d_in[2];
    const float4* W4  = (const float4*)d_in[3];
    const float*  b   = (const float*)d_in[4];
    float4* out4 = (float4*)d_out;

    int nNodes = in_sizes[0] / NF;   // 50000
    int nE4    = in_sizes[1] / 4;    // 200000

    float2* S = (float2*)d_ws;       // 50000*8 B = 400 KB scratch

    void* args[] = { (void*)&h4, (void*)&W4, (void*)&S, (void*)&nNodes,
                     (void*)&src, (void*)&dst, (void*)&b,
                     (void*)&out4, (void*)&nE4 };
    hipLaunchCooperativeKernel((void*)fused_kernel, dim3(NBLOCKS), dim3(NTHREADS),
                               args, 0, stream);
}

// Round 4
// 18.146 us; speedup vs baseline: 3.9327x; 3.9327x over previous
//
#include <hip/hip_runtime.h>
#include <math.h>

#define NF 64  // IN_FEATS

// ---------------------------------------------------------------------------
// Kernel 1: per-node scores.  S[n] = (h[n]·W_u + b,  h[n]·W_v)
// One thread per node: 16 independent float4 loads (256 B/thread, full lines
// used via L1; 16 KB in flight per wave), W held uniform (SGPR), dual dot
// product in registers, single 8 B store. No shuffles, no divergence.
// ---------------------------------------------------------------------------
__global__ void __launch_bounds__(128)
node_scores_kernel(const float4* __restrict__ h4,
                   const float4* __restrict__ W4,
                   const float* __restrict__ b,
                   float2* __restrict__ S, int nNodes) {
    int n = blockIdx.x * blockDim.x + threadIdx.x;
    if (n >= nNodes) return;

    const float4* row = h4 + (size_t)n * 16;
    float su = b[0], sv = 0.0f;
    #pragma unroll
    for (int j = 0; j < 16; ++j) {
        float4 x  = row[j];
        float4 wu = W4[j];        // uniform -> s_load, stays scalar
        float4 wv = W4[16 + j];
        su += x.x * wu.x + x.y * wu.y + x.z * wu.z + x.w * wu.w;
        sv += x.x * wv.x + x.y * wv.y + x.z * wv.z + x.w * wv.w;
    }
    S[n] = make_float2(su, sv);
}

// ---------------------------------------------------------------------------
// Kernel 2: out[e] = sigmoid(S[src[e]].x + S[dst[e]].y), 8 edges/thread.
// 16 independent S-gathers per thread hide L2 latency; int4 index loads;
// two float4 stores. Index dtype (int64 vs int32) detected per-wave from
// the first 512 B of src (int64 ids < 2^31 => every odd dword is 0).
// ---------------------------------------------------------------------------
__global__ void __launch_bounds__(256)
edge_kernel(const void* __restrict__ srcv,
            const void* __restrict__ dstv,
            const float2* __restrict__ S,
            float4* __restrict__ out4, int nT) {
    int lane = threadIdx.x & 63;
    int odd = ((const int*)srcv)[2 * lane + 1];
    bool is64 = (__ballot(odd == 0) == ~0ull);  // wave-uniform

    int t = blockIdx.x * blockDim.x + threadIdx.x;
    if (t >= nT) return;

    int si[8], di[8];
    if (is64) {
        const int4* sp = (const int4*)srcv + 4 * t;  // 64 B = 8 int64
        const int4* dp = (const int4*)dstv + 4 * t;
        int4 a = sp[0], b_ = sp[1], c = sp[2], d = sp[3];
        si[0] = a.x; si[1] = a.z; si[2] = b_.x; si[3] = b_.z;
        si[4] = c.x; si[5] = c.z; si[6] = d.x;  si[7] = d.z;
        int4 e = dp[0], f = dp[1], g = dp[2], k = dp[3];
        di[0] = e.x; di[1] = e.z; di[2] = f.x; di[3] = f.z;
        di[4] = g.x; di[5] = g.z; di[6] = k.x; di[7] = k.z;
    } else {
        const int4* sp = (const int4*)srcv + 2 * t;  // 32 B = 8 int32
        const int4* dp = (const int4*)dstv + 2 * t;
        int4 a = sp[0], b_ = sp[1];
        si[0] = a.x; si[1] = a.y; si[2] = a.z; si[3] = a.w;
        si[4] = b_.x; si[5] = b_.y; si[6] = b_.z; si[7] = b_.w;
        int4 e = dp[0], f = dp[1];
        di[0] = e.x; di[1] = e.y; di[2] = e.z; di[3] = e.w;
        di[4] = f.x; di[5] = f.y; di[6] = f.z; di[7] = f.w;
    }

    float2 su[8], dv[8];
    #pragma unroll
    for (int j = 0; j < 8; ++j) su[j] = S[si[j]];   // independent gathers
    #pragma unroll
    for (int j = 0; j < 8; ++j) dv[j] = S[di[j]];

    float o[8];
    #pragma unroll
    for (int j = 0; j < 8; ++j) {
        float l = su[j].x + dv[j].y;                // bias already in S.x
        o[j] = 1.0f / (1.0f + __expf(-l));
    }
    out4[2 * t]     = make_float4(o[0], o[1], o[2], o[3]);
    out4[2 * t + 1] = make_float4(o[4], o[5], o[6], o[7]);
}

extern "C" void kernel_launch(void* const* d_in, const int* in_sizes, int n_in,
                              void* d_out, int out_size, void* d_ws, size_t ws_size,
                              hipStream_t stream) {
    const float4* h4  = (const float4*)d_in[0];
    const void*   src = d_in[1];
    const void*   dst = d_in[2];
    const float4* W4  = (const float4*)d_in[3];
    const float*  b   = (const float*)d_in[4];
    float4* out4 = (float4*)d_out;

    int nNodes = in_sizes[0] / NF;   // 50000
    int nE     = in_sizes[1];        // 800000

    float2* S = (float2*)d_ws;       // 50000*8 B = 400 KB scratch

    int nodeBlocks = (nNodes + 127) / 128;       // 391 blocks of 128
    node_scores_kernel<<<nodeBlocks, 128, 0, stream>>>(h4, W4, b, S, nNodes);

    int nT = nE / 8;                             // 100000 threads
    int edgeBlocks = (nT + 255) / 256;           // 391 blocks of 256
    edge_kernel<<<edgeBlocks, 256, 0, stream>>>(src, dst, S, out4, nT);
}